// Round 4
// baseline (90.179 us; speedup 1.0000x reference)
//
#include <hip/hip_runtime.h>

// QuantizedLinear: out[t][o] = sum_k x[t][k] * (w_q[o][k]-128)*scale[o] + bias[o]
// M=16, N=8192, K=8192. Memory-bound on w_q (256 MB int32, read once).
//
// R2 change vs R1: occupancy. 32 KB LDS chunk (K_CHUNK=512) + 8 channels/block
// (W_O=2) -> 1024 blocks, 4 blocks/CU, 16 waves/CU (was 2 blocks/CU, 8 waves).
// Chunk's w-loads hoisted ahead of the FMA body (4 dwordx4 in flight/wave).
// (Resubmitted unchanged after round-2 and round-3 infra failures.)

#define IN_F   8192
#define OUT_F  8192
#define NT     16          // tokens
#define K_CHUNK 512
#define BLOCK  256
#define W_O    2           // output channels per wave
#define CH_PER_BLOCK 8     // 4 waves * W_O

__global__ __launch_bounds__(BLOCK, 4)
void qlin_kernel(const float* __restrict__ x,     // [16][8192]
                 const int*   __restrict__ w_q,   // [8192][8192]
                 const float* __restrict__ scale, // [8192]
                 const float* __restrict__ bias,  // [8192]
                 float* __restrict__ out)         // [16][8192]
{
    __shared__ float xs[NT][K_CHUNK];             // 32 KB

    const int tid  = threadIdx.x;
    const int lane = tid & 63;
    const int wave = tid >> 6;
    const int o_base = blockIdx.x * CH_PER_BLOCK + wave * W_O;

    float acc[NT][W_O];
#pragma unroll
    for (int t = 0; t < NT; ++t)
#pragma unroll
        for (int j = 0; j < W_O; ++j) acc[t][j] = 0.0f;

    const int nchunk = IN_F / K_CHUNK;            // 16

    for (int c = 0; c < nchunk; ++c) {
        __syncthreads();                          // xs safe to overwrite
        // ---- stage x chunk: NT*K_CHUNK = 8192 floats, 8 float4/thread ----
#pragma unroll
        for (int r = 0; r < (NT * K_CHUNK) / (BLOCK * 4); ++r) {
            const int flat = r * (BLOCK * 4) + tid * 4;   // 0..8191
            const int i = flat >> 9;                      // /K_CHUNK
            const int k = flat & (K_CHUNK - 1);
            *reinterpret_cast<float4*>(&xs[i][k]) =
                *reinterpret_cast<const float4*>(
                    &x[(size_t)i * IN_F + c * K_CHUNK + k]);
        }
        __syncthreads();

        // ---- hoist the chunk's w loads: 2 rows x 2 segments of 256 k ----
        const int kl0 = lane * 4;           // k-in-chunk, segment 0
        const int kg  = c * K_CHUNK + kl0;  // global k
        int4 w0[W_O], w1[W_O];
#pragma unroll
        for (int j = 0; j < W_O; ++j) {
            const size_t row = (size_t)(o_base + j) * IN_F;
            w0[j] = *reinterpret_cast<const int4*>(&w_q[row + kg]);
            w1[j] = *reinterpret_cast<const int4*>(&w_q[row + kg + 256]);
        }

        float wf[W_O][4];
        // ---- segment 0 ----
#pragma unroll
        for (int j = 0; j < W_O; ++j) {
            wf[j][0] = (float)(w0[j].x - 128);
            wf[j][1] = (float)(w0[j].y - 128);
            wf[j][2] = (float)(w0[j].z - 128);
            wf[j][3] = (float)(w0[j].w - 128);
        }
#pragma unroll
        for (int t = 0; t < NT; ++t) {
            const float4 xv = *reinterpret_cast<const float4*>(&xs[t][kl0]);
#pragma unroll
            for (int j = 0; j < W_O; ++j) {
                acc[t][j] += wf[j][0] * xv.x;
                acc[t][j] += wf[j][1] * xv.y;
                acc[t][j] += wf[j][2] * xv.z;
                acc[t][j] += wf[j][3] * xv.w;
            }
        }
        // ---- segment 1 ----
#pragma unroll
        for (int j = 0; j < W_O; ++j) {
            wf[j][0] = (float)(w1[j].x - 128);
            wf[j][1] = (float)(w1[j].y - 128);
            wf[j][2] = (float)(w1[j].z - 128);
            wf[j][3] = (float)(w1[j].w - 128);
        }
#pragma unroll
        for (int t = 0; t < NT; ++t) {
            const float4 xv = *reinterpret_cast<const float4*>(&xs[t][kl0 + 256]);
#pragma unroll
            for (int j = 0; j < W_O; ++j) {
                acc[t][j] += wf[j][0] * xv.x;
                acc[t][j] += wf[j][1] * xv.y;
                acc[t][j] += wf[j][2] * xv.z;
                acc[t][j] += wf[j][3] * xv.w;
            }
        }
    }

    // ---- cross-lane reduction: 32 (t,j) values, 6-step butterfly each ----
    float myval = 0.0f;
#pragma unroll
    for (int t = 0; t < NT; ++t) {
#pragma unroll
        for (int j = 0; j < W_O; ++j) {
            float v = acc[t][j];
#pragma unroll
            for (int off = 32; off > 0; off >>= 1)
                v += __shfl_xor(v, off, 64);
            if (lane == (t * W_O + j)) myval = v;
        }
    }

    // lane l (<32) -> t = l>>1, channel j = l&1
    if (lane < NT * W_O) {
        const int t_o = lane >> 1;
        const int o   = o_base + (lane & 1);
        out[(size_t)t_o * OUT_F + o] = myval * scale[o] + bias[o];
    }
}

extern "C" void kernel_launch(void* const* d_in, const int* in_sizes, int n_in,
                              void* d_out, int out_size, void* d_ws, size_t ws_size,
                              hipStream_t stream) {
    const float* x     = (const float*)d_in[0];
    const int*   w_q   = (const int*)d_in[1];
    const float* scale = (const float*)d_in[2];
    const float* bias  = (const float*)d_in[3];
    float*       out   = (float*)d_out;

    dim3 grid(OUT_F / CH_PER_BLOCK);   // 1024 blocks -> 4 per CU
    dim3 block(BLOCK);
    qlin_kernel<<<grid, block, 0, stream>>>(x, w_q, scale, bias, out);
}

// Round 6
// 75.700 us; speedup vs baseline: 1.1913x; 1.1913x over previous
//
#include <hip/hip_runtime.h>

// QuantizedLinear: out[t][o] = sum_k x[t][k] * (w_q[o][k]-128)*scale[o] + bias[o]
// M=16, N=8192, K=8192. Memory-bound on w_q (256 MB int32, read once).
//
// R5 structure: barrier-free pure stream. NO LDS, NO __syncthreads.
// x (512 KB) is L2/L3-resident and read directly from global per k-step
// (16 KB window per k-step is L1-hot; x:w byte ratio 4:1 -> ~24 TB/s
// aggregate from L1/L2, under ceiling). Each wave owns 4 output rows and
// streams them over full K as independent dwordx4 loads -- the same
// dependency-free pattern that lets fillBuffer hit 7 TB/s at 10% occupancy.
// R1 (82 us) and R4 (90 us) showed the barrier+staging structure, not
// occupancy, was the limiter.
// (Resubmitted unchanged after round-5 infra failure.)

#define IN_F   8192
#define OUT_F  8192
#define NT     16          // tokens
#define BLOCK  256
#define W_O    4           // output channels per wave
#define CH_PER_BLOCK 16    // 4 waves * W_O

__global__ __launch_bounds__(BLOCK, 2)
void qlin_kernel(const float* __restrict__ x,     // [16][8192]
                 const int*   __restrict__ w_q,   // [8192][8192]
                 const float* __restrict__ scale, // [8192]
                 const float* __restrict__ bias,  // [8192]
                 float* __restrict__ out)         // [16][8192]
{
    const int tid  = threadIdx.x;
    const int lane = tid & 63;
    const int wave = tid >> 6;
    const int o_base = blockIdx.x * CH_PER_BLOCK + wave * W_O;

    const int* __restrict__ wr0 = w_q + (size_t)(o_base + 0) * IN_F;
    const int* __restrict__ wr1 = w_q + (size_t)(o_base + 1) * IN_F;
    const int* __restrict__ wr2 = w_q + (size_t)(o_base + 2) * IN_F;
    const int* __restrict__ wr3 = w_q + (size_t)(o_base + 3) * IN_F;

    float acc[NT][W_O];
#pragma unroll
    for (int t = 0; t < NT; ++t)
#pragma unroll
        for (int j = 0; j < W_O; ++j) acc[t][j] = 0.0f;

    // 32 k-steps; each covers 256 k (64 lanes x int4). No barriers anywhere.
#pragma unroll 2
    for (int ks = 0; ks < IN_F / 256; ++ks) {
        const int k = ks * 256 + lane * 4;

        const int4 w0 = *reinterpret_cast<const int4*>(wr0 + k);
        const int4 w1 = *reinterpret_cast<const int4*>(wr1 + k);
        const int4 w2 = *reinterpret_cast<const int4*>(wr2 + k);
        const int4 w3 = *reinterpret_cast<const int4*>(wr3 + k);

        float wf[W_O][4];
        wf[0][0] = (float)(w0.x - 128); wf[0][1] = (float)(w0.y - 128);
        wf[0][2] = (float)(w0.z - 128); wf[0][3] = (float)(w0.w - 128);
        wf[1][0] = (float)(w1.x - 128); wf[1][1] = (float)(w1.y - 128);
        wf[1][2] = (float)(w1.z - 128); wf[1][3] = (float)(w1.w - 128);
        wf[2][0] = (float)(w2.x - 128); wf[2][1] = (float)(w2.y - 128);
        wf[2][2] = (float)(w2.z - 128); wf[2][3] = (float)(w2.w - 128);
        wf[3][0] = (float)(w3.x - 128); wf[3][1] = (float)(w3.y - 128);
        wf[3][2] = (float)(w3.z - 128); wf[3][3] = (float)(w3.w - 128);

#pragma unroll
        for (int t = 0; t < NT; ++t) {
            const float4 xv = *reinterpret_cast<const float4*>(
                &x[(size_t)t * IN_F + k]);            // L1/L2-hot
#pragma unroll
            for (int j = 0; j < W_O; ++j) {
                acc[t][j] += wf[j][0] * xv.x;
                acc[t][j] += wf[j][1] * xv.y;
                acc[t][j] += wf[j][2] * xv.z;
                acc[t][j] += wf[j][3] * xv.w;
            }
        }
    }

    // ---- cross-lane reduction: 64 (t,j) values, 6-step butterfly each ----
    float myval = 0.0f;
#pragma unroll
    for (int t = 0; t < NT; ++t) {
#pragma unroll
        for (int j = 0; j < W_O; ++j) {
            float v = acc[t][j];
#pragma unroll
            for (int off = 32; off > 0; off >>= 1)
                v += __shfl_xor(v, off, 64);
            if (lane == (t * W_O + j)) myval = v;
        }
    }

    // lane l -> (t = l>>2, channel j = l&3)
    const int t_o = lane >> 2;
    const int o   = o_base + (lane & 3);
    out[(size_t)t_o * OUT_F + o] = myval * scale[o] + bias[o];
}

extern "C" void kernel_launch(void* const* d_in, const int* in_sizes, int n_in,
                              void* d_out, int out_size, void* d_ws, size_t ws_size,
                              hipStream_t stream) {
    const float* x     = (const float*)d_in[0];
    const int*   w_q   = (const int*)d_in[1];
    const float* scale = (const float*)d_in[2];
    const float* bias  = (const float*)d_in[3];
    float*       out   = (float*)d_out;

    dim3 grid(OUT_F / CH_PER_BLOCK);   // 512 blocks -> 2 per CU
    dim3 block(BLOCK);
    qlin_kernel<<<grid, block, 0, stream>>>(x, w_q, scale, bias, out);
}